// Round 18
// baseline (80.395 us; speedup 1.0000x reference)
//
#include <hip/hip_runtime.h>
#include <hip/hip_bf16.h>
#include <cstdint>
#include <cstddef>

typedef float f32x4  __attribute__((ext_vector_type(4)));
typedef short bf16x8 __attribute__((ext_vector_type(8)));
typedef int   i32x4  __attribute__((ext_vector_type(4)));

#define LN_EPS 1e-5f

static __device__ __forceinline__ unsigned short f2bf(float f) {
    __hip_bfloat16 h = __float2bfloat16(f);          // native RNE cvt
    union { __hip_bfloat16 b; unsigned short u; } cv; cv.b = h;
    return cv.u;
}
static __device__ __forceinline__ float bf2f(unsigned short h) {
    return __uint_as_float(((unsigned int)h) << 16);
}

// ---- combined prep (1 launch):
//   blocks 0..287:   W2 = g .* W  (192x384 f32) -> bf16 in MFMA B-frag order
//   blocks 288..335: s2[o] = sum_i g[i]W[o][i], c0[o] = sum_i b[i]W[o][i]
__global__ void prep_all_kernel(const float* __restrict__ W,
                                const float* __restrict__ g,
                                const float* __restrict__ b,
                                unsigned short* __restrict__ wsh,
                                float* __restrict__ s2,
                                float* __restrict__ c0) {
    const int bid = blockIdx.x;
    const int tid = threadIdx.x;
    if (bid < 288) {
        int o = bid * 256 + tid;
        if (o >= 192 * 384) return;
        int j    = o & 7;
        int lane = (o >> 3) & 63;
        int t    = o >> 9;
        int nf   = t % 12;
        int kk   = t / 12;
        int n = nf * 16 + (lane & 15);
        int k = kk * 32 + (lane >> 4) * 8 + j;
        wsh[o] = f2bf(g[k] * W[n * 384 + k]);
    } else {
        const int o = (bid - 288) * 4 + (tid >> 6);    // output row 0..191
        const int j = tid & 63;                        // lane
        const float* wr = W + o * 384;
        float a = 0.f, c = 0.f;
        #pragma unroll
        for (int i = 0; i < 6; i++) {
            const int k = j + 64 * i;
            float w = wr[k];
            a += g[k] * w; c += b[k] * w;
        }
        #pragma unroll
        for (int d = 1; d < 64; d <<= 1) { a += __shfl_xor(a, d); c += __shfl_xor(c, d); }
        if (j == 0) { s2[o] = a; c0[o] = c; }
    }
}

// ====== main fused kernel: COALESCED linear staging, full 49152 B tile ======
// Stream order (3072 float4 chunks / block): s = h-parity segment (0,1), then
// w ascending (64 pixels/segment), then within-pixel float4 f = 0..23.
// Consecutive chunks = consecutive memory (two ~24.6 KB contiguous segments).
__global__ __launch_bounds__(256, 3)
void fused_coal(const float* __restrict__ x,
                const unsigned short* __restrict__ wsh,
                const float* __restrict__ s2p, const float* __restrict__ c0p,
                const float* __restrict__ vw, const float* __restrict__ vb,
                const float* __restrict__ aw, const float* __restrict__ ab,
                const float* __restrict__ fw, const float* __restrict__ fb,
                float* __restrict__ out) {
    // [0,24576): A-hi bf16 32x384 swizzled ; [24576,49152): A-lo ;
    // xs f32 [32][196] (25088 B) overlays from 0 after MFMA.
    __shared__ __align__(16) unsigned char lds[49152];

    const int tid = threadIdx.x;
    const int r   = tid >> 3;        // row 0..31 (stats + epilogue mapping)
    const int u   = tid & 7;         // 8 threads/row

    const int wv = tid >> 6;
    const int l  = tid & 63;
    const int g  = l >> 4;
    const int cl = l & 15;

    const int R0 = blockIdx.x * 32;

    // ---------------- coalesced stage: linear chunks -> pack hi/lo -> LDS scatter ----
    #pragma unroll
    for (int j = 0; j < 12; j++) {
        const int c  = tid + 256 * j;              // stream chunk 0..3071
        const int s  = (c >= 1536) ? 1 : 0;        // h-parity segment
        const int d  = c - 1536 * s;
        const int pw = d / 24;                     // pixel 0..63 within segment
        const int f  = d - pw * 24;                // float4 within pixel 0..23
        const int rc = pw >> 1;                    // owning output row 0..31
        const int pb = pw & 1;                     // w-parity
        const int R   = R0 + rc;
        const int bb  = R / 12544;
        const int rem = R - bb * 12544;
        const int h2  = rem / 112;
        const int w2  = rem - h2 * 112;
        const f32x4* px = (const f32x4*)(x + (((size_t)bb * 224 + 2 * h2 + s) * 224
                                              + 2 * w2 + pb) * 96);
        f32x4 val = px[f];

        union { unsigned short u16[4]; unsigned long long u64; } hi8, lo8;
        #pragma unroll
        for (int e = 0; e < 4; e++) {
            unsigned short hi = f2bf(val[e]);
            hi8.u16[e] = hi;
            lo8.u16[e] = f2bf(val[e] - bf2f(hi));
        }
        const int hh   = (f >= 12) ? 1 : 0;
        const int fm   = f - 12 * hh;
        const int p    = fm >> 1;
        const int half = fm & 1;
        const int q    = s + 2 * pb;               // concat order x0,x1,x2,x3
        const int sl   = 6 * (2 * q + hh) + p;     // 16B slot 0..47 in row
        const int boff = ((sl * 16) ^ ((rc & 7) << 4)) + half * 8;
        *(unsigned long long*)(&lds[rc * 768 + boff])         = hi8.u64;
        *(unsigned long long*)(&lds[24576 + rc * 768 + boff]) = lo8.u64;
    }
    __syncthreads();

    // ---------------- LN(merge) stats via read-back (thread r,u owns 48 cols) --------
    float mu, rs;
    {
        f32x4 v[12];
        #pragma unroll
        for (int p = 0; p < 6; p++) {
            const int boff = ((6 * u + p) * 16) ^ ((r & 7) << 4);
            bf16x8 hb = *(const bf16x8*)(&lds[r * 768 + boff]);
            bf16x8 lb = *(const bf16x8*)(&lds[24576 + r * 768 + boff]);
            #pragma unroll
            for (int k = 0; k < 8; k++)
                v[2 * p + (k >> 2)][k & 3] =
                    bf2f((unsigned short)hb[k]) + bf2f((unsigned short)lb[k]);
        }
        float s = 0.f;
        #pragma unroll
        for (int i = 0; i < 12; i++) {
            #pragma unroll
            for (int e = 0; e < 4; e++) s += v[i][e];
        }
        s += __shfl_xor(s, 1); s += __shfl_xor(s, 2); s += __shfl_xor(s, 4);
        mu = s * (1.f / 384.f);
        float sd = 0.f;
        #pragma unroll
        for (int i = 0; i < 12; i++) {
            #pragma unroll
            for (int e = 0; e < 4; e++) { float dd = v[i][e] - mu; sd += dd * dd; }
        }
        sd += __shfl_xor(sd, 1); sd += __shfl_xor(sd, 2); sd += __shfl_xor(sd, 4);
        rs = rsqrtf(sd * (1.f / 384.f) + LN_EPS);
    }

    // ---------------- MFMA: wave wv -> rows 0..31 x cols [48wv,48wv+48), 2-pass ------
    f32x4 acc[2][3];
    #pragma unroll
    for (int mf = 0; mf < 2; mf++)
        #pragma unroll
        for (int t = 0; t < 3; t++) acc[mf][t] = (f32x4){0.f, 0.f, 0.f, 0.f};

    #pragma unroll
    for (int kk = 0; kk < 12; kk++) {
        bf16x8 bh[3];
        const bf16x8* bph = (const bf16x8*)wsh + ((kk * 12 + 3 * wv) * 64 + l);
        bh[0] = bph[0]; bh[1] = bph[64]; bh[2] = bph[128];
        #pragma unroll
        for (int mf = 0; mf < 2; mf++) {
            const int row  = 16 * mf + cl;
            const int boff = (kk * 64 + g * 16) ^ ((row & 7) << 4);
            bf16x8 afh = *(const bf16x8*)(&lds[row * 768 + boff]);
            bf16x8 afl = *(const bf16x8*)(&lds[24576 + row * 768 + boff]);
            #pragma unroll
            for (int t = 0; t < 3; t++) {
                acc[mf][t] = __builtin_amdgcn_mfma_f32_16x16x32_bf16(afh, bh[t], acc[mf][t], 0, 0, 0);
                acc[mf][t] = __builtin_amdgcn_mfma_f32_16x16x32_bf16(afl, bh[t], acc[mf][t], 0, 0, 0);
            }
        }
    }
    __syncthreads();   // all A-reads done; reuse LDS for xs

    // ---------------- xs(raw acc) -> LDS f32 [32][196] ----------------
    {
        float* xsl = (float*)lds;
        #pragma unroll
        for (int mf = 0; mf < 2; mf++)
            #pragma unroll
            for (int t = 0; t < 3; t++) {
                const int col = 48 * wv + 16 * t + cl;   // D: col=lane&15, row=4*(lane>>4)+reg
                #pragma unroll
                for (int rg = 0; rg < 4; rg++) {
                    const int row = 16 * mf + 4 * g + rg;
                    xsl[row * 196 + col] = acc[mf][t][rg];
                }
            }
    }
    __syncthreads();

    // ---------------- epilogue: folded merge-LN affine + 3 chained LNs ----------------
    {
        const float* rowp = (const float*)lds + r * 196 + u * 24;
        float vv[24];
        #pragma unroll
        for (int i = 0; i < 6; i++) {
            f32x4 t4 = *(const f32x4*)(rowp + 4 * i);
            #pragma unroll
            for (int e = 0; e < 4; e++) vv[4 * i + e] = t4[e];
        }
        {
            const f32x4* s2v = (const f32x4*)(s2p + u * 24);
            const f32x4* c0v = (const f32x4*)(c0p + u * 24);
            #pragma unroll
            for (int i = 0; i < 6; i++) {
                f32x4 sv = s2v[i], cv = c0v[i];
                #pragma unroll
                for (int e = 0; e < 4; e++)
                    vv[4 * i + e] = rs * (vv[4 * i + e] - mu * sv[e]) + cv[e];
            }
        }
        float s1 = 0.f;
        #pragma unroll
        for (int i = 0; i < 24; i++) s1 += vv[i];
        s1 += __shfl_xor(s1, 1); s1 += __shfl_xor(s1, 2); s1 += __shfl_xor(s1, 4);
        const float mu1 = s1 * (1.f / 192.f);
        float d1 = 0.f;
        #pragma unroll
        for (int i = 0; i < 24; i++) { float d = vv[i] - mu1; d1 += d * d; }
        d1 += __shfl_xor(d1, 1); d1 += __shfl_xor(d1, 2); d1 += __shfl_xor(d1, 4);
        const float r1 = rsqrtf(d1 * (1.f / 192.f) + LN_EPS);

        const f32x4* vwv = (const f32x4*)(vw + u * 24);
        const f32x4* vbv = (const f32x4*)(vb + u * 24);
        float s2s = 0.f;
        #pragma unroll
        for (int i = 0; i < 6; i++) {
            f32x4 w4 = vwv[i], b4 = vbv[i];
            #pragma unroll
            for (int e = 0; e < 4; e++) {
                float xs0 = vv[4 * i + e];
                float xv0 = xs0 + (xs0 - mu1) * r1 * w4[e] + b4[e];
                vv[4 * i + e] = xv0;
                s2s += xv0;
            }
        }
        s2s += __shfl_xor(s2s, 1); s2s += __shfl_xor(s2s, 2); s2s += __shfl_xor(s2s, 4);
        const float mu2 = s2s * (1.f / 192.f);
        float d2 = 0.f;
        #pragma unroll
        for (int i = 0; i < 24; i++) { float d = vv[i] - mu2; d2 += d * d; }
        d2 += __shfl_xor(d2, 1); d2 += __shfl_xor(d2, 2); d2 += __shfl_xor(d2, 4);
        const float r2 = rsqrtf(d2 * (1.f / 192.f) + LN_EPS);

        const f32x4* awv = (const f32x4*)(aw + u * 24);
        const f32x4* abv = (const f32x4*)(ab + u * 24);
        float s3 = 0.f;
        #pragma unroll
        for (int i = 0; i < 6; i++) {
            f32x4 w4 = awv[i], b4 = abv[i];
            #pragma unroll
            for (int e = 0; e < 4; e++) {
                float xa0 = (vv[4 * i + e] - mu2) * r2 * w4[e] + b4[e];
                vv[4 * i + e] = xa0;
                s3 += xa0;
            }
        }
        s3 += __shfl_xor(s3, 1); s3 += __shfl_xor(s3, 2); s3 += __shfl_xor(s3, 4);
        const float mu3 = s3 * (1.f / 192.f);
        float d3 = 0.f;
        #pragma unroll
        for (int i = 0; i < 24; i++) { float d = vv[i] - mu3; d3 += d * d; }
        d3 += __shfl_xor(d3, 1); d3 += __shfl_xor(d3, 2); d3 += __shfl_xor(d3, 4);
        const float r3 = rsqrtf(d3 * (1.f / 192.f) + LN_EPS);

        const f32x4* fwv = (const f32x4*)(fw + u * 24);
        const f32x4* fbv = (const f32x4*)(fb + u * 24);
        float* op = out + (size_t)(R0 + r) * 192 + u * 24;
        #pragma unroll
        for (int i = 0; i < 6; i++) {
            f32x4 w4 = fwv[i], b4 = fbv[i];
            f32x4 o4;
            #pragma unroll
            for (int e = 0; e < 4; e++)
                o4[e] = (vv[4 * i + e] - mu3) * r3 * w4[e] + b4[e];
            *(f32x4*)(op + 4 * i) = o4;
        }
    }
}

// =============== fallback (no workspace): round-8 style fused, inline W cvt ===============
__global__ __launch_bounds__(256, 3)
void fused_fallback(const float* __restrict__ x,
                    const float* __restrict__ Wf,
                    const float* __restrict__ mw, const float* __restrict__ mb,
                    const float* __restrict__ vw, const float* __restrict__ vb,
                    const float* __restrict__ aw, const float* __restrict__ ab,
                    const float* __restrict__ fw, const float* __restrict__ fb,
                    float* __restrict__ out) {
    __shared__ __align__(16) unsigned char lds[49152];
    const int tid = threadIdx.x;
    const int r   = tid >> 3;
    const int u   = tid & 7;
    const int q   = u >> 1;
    const int hh  = u & 1;
    const int wv = tid >> 6;
    const int l  = tid & 63;
    const int g  = l >> 4;
    const int cl = l & 15;

    {
        const int R   = blockIdx.x * 32 + r;
        const int b   = R / 12544;
        const int rem = R - b * 12544;
        const int h2  = rem / 112;
        const int w2  = rem - h2 * 112;
        const int h   = 2 * h2 + (q & 1);
        const int w   = 2 * w2 + (q >> 1);
        const f32x4* src = (const f32x4*)(x + (((size_t)b * 224 + h) * 224 + w) * 96 + hh * 48);
        f32x4 v[12];
        #pragma unroll
        for (int i = 0; i < 12; i++) v[i] = src[i];
        float s = 0.f;
        #pragma unroll
        for (int i = 0; i < 12; i++)
            #pragma unroll
            for (int e = 0; e < 4; e++) s += v[i][e];
        s += __shfl_xor(s, 1); s += __shfl_xor(s, 2); s += __shfl_xor(s, 4);
        const float mu = s * (1.f / 384.f);
        float sd = 0.f;
        #pragma unroll
        for (int i = 0; i < 12; i++)
            #pragma unroll
            for (int e = 0; e < 4; e++) { float d = v[i][e] - mu; sd += d * d; }
        sd += __shfl_xor(sd, 1); sd += __shfl_xor(sd, 2); sd += __shfl_xor(sd, 4);
        const float rs = rsqrtf(sd * (1.f / 384.f) + LN_EPS);
        const f32x4* mwv = (const f32x4*)(mw + q * 96 + hh * 48);
        const f32x4* mbv = (const f32x4*)(mb + q * 96 + hh * 48);
        #pragma unroll
        for (int p = 0; p < 6; p++) {
            union { unsigned short u16[8]; i32x4 v4; } ph, pl;
            #pragma unroll
            for (int half = 0; half < 2; half++) {
                const int i = 2 * p + half;
                f32x4 w4 = mwv[i], b4 = mbv[i];
                #pragma unroll
                for (int e = 0; e < 4; e++) {
                    float a = (v[i][e] - mu) * rs * w4[e] + b4[e];
                    unsigned short hi = f2bf(a);
                    ph.u16[4 * half + e] = hi;
                    pl.u16[4 * half + e] = f2bf(a - bf2f(hi));
                }
            }
            const int slot = 6 * u + p;
            const int boff = (slot * 16) ^ ((r & 7) << 4);
            *(i32x4*)(&lds[r * 768 + boff])         = ph.v4;
            *(i32x4*)(&lds[24576 + r * 768 + boff]) = pl.v4;
        }
    }
    __syncthreads();

    f32x4 acc[2][3];
    #pragma unroll
    for (int mf = 0; mf < 2; mf++)
        #pragma unroll
        for (int t = 0; t < 3; t++) acc[mf][t] = (f32x4){0.f, 0.f, 0.f, 0.f};
    #pragma unroll
    for (int kk = 0; kk < 12; kk++) {
        bf16x8 bh[3];
        #pragma unroll
        for (int t = 0; t < 3; t++) {
            const int n = (3 * wv + t) * 16 + cl;
            const float* wp = Wf + n * 384 + kk * 32 + g * 8;
            f32x4 lo = *(const f32x4*)wp;
            f32x4 hi4 = *(const f32x4*)(wp + 4);
            bf16x8 hbb;
            #pragma unroll
            for (int e = 0; e < 4; e++) { hbb[e] = (short)f2bf(lo[e]); hbb[4 + e] = (short)f2bf(hi4[e]); }
            bh[t] = hbb;
        }
        #pragma unroll
        for (int mf = 0; mf < 2; mf++) {
            const int row  = 16 * mf + cl;
            const int boff = (kk * 64 + g * 16) ^ ((row & 7) << 4);
            bf16x8 afh = *(const bf16x8*)(&lds[row * 768 + boff]);
            bf16x8 afl = *(const bf16x8*)(&lds[24576 + row * 768 + boff]);
            #pragma unroll
            for (int t = 0; t < 3; t++) {
                acc[mf][t] = __builtin_amdgcn_mfma_f32_16x16x32_bf16(afh, bh[t], acc[mf][t], 0, 0, 0);
                acc[mf][t] = __builtin_amdgcn_mfma_f32_16x16x32_bf16(afl, bh[t], acc[mf][t], 0, 0, 0);
            }
        }
    }
    __syncthreads();
    {
        float* xsl = (float*)lds;
        #pragma unroll
        for (int mf = 0; mf < 2; mf++)
            #pragma unroll
            for (int t = 0; t < 3; t++) {
                const int col = 48 * wv + 16 * t + cl;
                #pragma unroll
                for (int rg = 0; rg < 4; rg++) {
                    const int row = 16 * mf + 4 * g + rg;
                    xsl[row * 196 + col] = acc[mf][t][rg];
                }
            }
    }
    __syncthreads();
    {
        const float* rowp = (const float*)lds + r * 196 + u * 24;
        float vv[24];
        #pragma unroll
        for (int i = 0; i < 6; i++) {
            f32x4 t4 = *(const f32x4*)(rowp + 4 * i);
            #pragma unroll
            for (int e = 0; e < 4; e++) vv[4 * i + e] = t4[e];
        }
        float s1 = 0.f;
        #pragma unroll
        for (int i = 0; i < 24; i++) s1 += vv[i];
        s1 += __shfl_xor(s1, 1); s1 += __shfl_xor(s1, 2); s1 += __shfl_xor(s1, 4);
        const float mu1 = s1 * (1.f / 192.f);
        float d1 = 0.f;
        #pragma unroll
        for (int i = 0; i < 24; i++) { float d = vv[i] - mu1; d1 += d * d; }
        d1 += __shfl_xor(d1, 1); d1 += __shfl_xor(d1, 2); d1 += __shfl_xor(d1, 4);
        const float r1 = rsqrtf(d1 * (1.f / 192.f) + LN_EPS);
        const f32x4* vwv = (const f32x4*)(vw + u * 24);
        const f32x4* vbv = (const f32x4*)(vb + u * 24);
        float s2s = 0.f;
        #pragma unroll
        for (int i = 0; i < 6; i++) {
            f32x4 w4 = vwv[i], b4 = vbv[i];
            #pragma unroll
            for (int e = 0; e < 4; e++) {
                float xs0 = vv[4 * i + e];
                float xv0 = xs0 + (xs0 - mu1) * r1 * w4[e] + b4[e];
                vv[4 * i + e] = xv0;
                s2s += xv0;
            }
        }
        s2s += __shfl_xor(s2s, 1); s2s += __shfl_xor(s2s, 2); s2s += __shfl_xor(s2s, 4);
        const float mu2 = s2s * (1.f / 192.f);
        float d2 = 0.f;
        #pragma unroll
        for (int i = 0; i < 24; i++) { float d = vv[i] - mu2; d2 += d * d; }
        d2 += __shfl_xor(d2, 1); d2 += __shfl_xor(d2, 2); d2 += __shfl_xor(d2, 4);
        const float r2 = rsqrtf(d2 * (1.f / 192.f) + LN_EPS);
        const f32x4* awv = (const f32x4*)(aw + u * 24);
        const f32x4* abv = (const f32x4*)(ab + u * 24);
        float s3 = 0.f;
        #pragma unroll
        for (int i = 0; i < 6; i++) {
            f32x4 w4 = awv[i], b4 = abv[i];
            #pragma unroll
            for (int e = 0; e < 4; e++) {
                float xa0 = (vv[4 * i + e] - mu2) * r2 * w4[e] + b4[e];
                vv[4 * i + e] = xa0;
                s3 += xa0;
            }
        }
        s3 += __shfl_xor(s3, 1); s3 += __shfl_xor(s3, 2); s3 += __shfl_xor(s3, 4);
        const float mu3 = s3 * (1.f / 192.f);
        float d3 = 0.f;
        #pragma unroll
        for (int i = 0; i < 24; i++) { float d = vv[i] - mu3; d3 += d * d; }
        d3 += __shfl_xor(d3, 1); d3 += __shfl_xor(d3, 2); d3 += __shfl_xor(d3, 4);
        const float r3 = rsqrtf(d3 * (1.f / 192.f) + LN_EPS);
        const f32x4* fwv = (const f32x4*)(fw + u * 24);
        const f32x4* fbv = (const f32x4*)(fb + u * 24);
        float* op = out + (size_t)(blockIdx.x * 32 + r) * 192 + u * 24;
        #pragma unroll
        for (int i = 0; i < 6; i++) {
            f32x4 w4 = fwv[i], b4 = fbv[i];
            f32x4 o4;
            #pragma unroll
            for (int e = 0; e < 4; e++)
                o4[e] = (vv[4 * i + e] - mu3) * r3 * w4[e] + b4[e];
            *(f32x4*)(op + 4 * i) = o4;
        }
    }
}

extern "C" void kernel_launch(void* const* d_in, const int* in_sizes, int n_in,
                              void* d_out, int out_size, void* d_ws, size_t ws_size,
                              hipStream_t stream) {
    const float* x  = (const float*)d_in[0];
    /* d_in[1] saliency_map: dead code in reference */
    const float* W  = (const float*)d_in[2];
    const float* mw = (const float*)d_in[3];
    const float* mb = (const float*)d_in[4];
    const float* vw = (const float*)d_in[5];
    const float* vb = (const float*)d_in[6];
    const float* aw = (const float*)d_in[7];
    const float* ab = (const float*)d_in[8];
    const float* fw = (const float*)d_in[9];
    const float* fb = (const float*)d_in[10];
    float* out = (float*)d_out;

    const int rows   = 8 * 112 * 112;     // 100352
    const int blocks = rows / 32;         // 3136

    unsigned short* wsh = (unsigned short*)d_ws;
    float* s2 = (float*)((char*)d_ws + 192 * 384 * 2);
    float* c0 = s2 + 192;

    if (ws_size >= (size_t)(192 * 384 * 2 + 2 * 192 * 4)) {
        prep_all_kernel<<<336, 256, 0, stream>>>(W, mw, mb, wsh, s2, c0);
        fused_coal<<<blocks, 256, 0, stream>>>(x, wsh, s2, c0,
                                               vw, vb, aw, ab, fw, fb, out);
    } else {
        fused_fallback<<<blocks, 256, 0, stream>>>(x, W, mw, mb, vw, vb,
                                                   aw, ab, fw, fb, out);
    }
}

// Round 19
// 77.398 us; speedup vs baseline: 1.0387x; 1.0387x over previous
//
#include <hip/hip_runtime.h>
#include <hip/hip_bf16.h>
#include <cstdint>
#include <cstddef>

typedef float f32x4  __attribute__((ext_vector_type(4)));
typedef short bf16x8 __attribute__((ext_vector_type(8)));
typedef int   i32x4  __attribute__((ext_vector_type(4)));

#define LN_EPS 1e-5f

static __device__ __forceinline__ unsigned short f2bf(float f) {
    __hip_bfloat16 h = __float2bfloat16(f);          // native RNE cvt
    union { __hip_bfloat16 b; unsigned short u; } cv; cv.b = h;
    return cv.u;
}
static __device__ __forceinline__ float bf2f(unsigned short h) {
    return __uint_as_float(((unsigned int)h) << 16);
}

// ---- combined prep (1 launch):
//   blocks 0..287:   W2 = g .* W  (192x384 f32) -> bf16 in MFMA B-frag order
//   blocks 288..335: s2[o] = sum_i g[i]W[o][i], c0[o] = sum_i b[i]W[o][i]
//                    (4 rows/block, one 64-lane wave per row)
__global__ void prep_all_kernel(const float* __restrict__ W,
                                const float* __restrict__ g,
                                const float* __restrict__ b,
                                unsigned short* __restrict__ wsh,
                                float* __restrict__ s2,
                                float* __restrict__ c0) {
    const int bid = blockIdx.x;
    const int tid = threadIdx.x;
    if (bid < 288) {
        int o = bid * 256 + tid;
        if (o >= 192 * 384) return;
        int j    = o & 7;
        int lane = (o >> 3) & 63;
        int t    = o >> 9;
        int nf   = t % 12;
        int kk   = t / 12;
        int n = nf * 16 + (lane & 15);
        int k = kk * 32 + (lane >> 4) * 8 + j;
        wsh[o] = f2bf(g[k] * W[n * 384 + k]);
    } else {
        const int o = (bid - 288) * 4 + (tid >> 6);    // output row 0..191
        const int j = tid & 63;                        // lane
        const float* wr = W + o * 384;
        float a = 0.f, c = 0.f;
        #pragma unroll
        for (int i = 0; i < 6; i++) {
            const int k = j + 64 * i;
            float w = wr[k];
            a += g[k] * w; c += b[k] * w;
        }
        #pragma unroll
        for (int d = 1; d < 64; d <<= 1) { a += __shfl_xor(a, d); c += __shfl_xor(c, d); }
        if (j == 0) { s2[o] = a; c0[o] = c; }
    }
}

// ====== main fused kernel (session best): K-split staging, 25088 B LDS,
// ====== PH/PL register carry, counted-vmcnt W pipeline, bound (256,3) ======
__global__ __launch_bounds__(256, 3)
void fused_split(const float* __restrict__ x,
                 const unsigned short* __restrict__ wsh,
                 const float* __restrict__ s2p, const float* __restrict__ c0p,
                 const float* __restrict__ vw, const float* __restrict__ vb,
                 const float* __restrict__ aw, const float* __restrict__ ab,
                 const float* __restrict__ fw, const float* __restrict__ fb,
                 float* __restrict__ out) {
    // stage window: [0,12288) A-hi (32 rows x 192 cols bf16, swizzled), [12288,24576) A-lo.
    // Reused for both K-phases. xs f32 [32][196] overlays [0,25088) after MFMA.
    __shared__ __align__(16) unsigned char lds[25088];

    const int tid = threadIdx.x;
    const int r   = tid >> 3;        // row 0..31
    const int u   = tid & 7;         // 8 threads/row; thread u owns cols [48u,48u+48)
    const int q   = u >> 1;          // patch chunk 0..3
    const int hh  = u & 1;           // half of 96-chunk

    const int wv = tid >> 6;
    const int l  = tid & 63;
    const int g  = l >> 4;
    const int cl = l & 15;

    float mu, rs;
    i32x4 PH[6], PL[6];              // this thread's 6 hi/lo 16B chunks

    // ---------------- gather raw x, pack hi/lo to regs, LN stats ----------------
    {
        const int R   = blockIdx.x * 32 + r;
        const int b   = R / 12544;
        const int rem = R - b * 12544;
        const int h2  = rem / 112;
        const int w2  = rem - h2 * 112;
        const int h   = 2 * h2 + (q & 1);       // x0,x1,x2,x3 concat order
        const int w   = 2 * w2 + (q >> 1);
        const f32x4* src = (const f32x4*)(x + (((size_t)b * 224 + h) * 224 + w) * 96 + hh * 48);
        f32x4 v[12];
        #pragma unroll
        for (int i = 0; i < 12; i++) v[i] = src[i];

        #pragma unroll
        for (int p = 0; p < 6; p++) {
            union { unsigned short u16[8]; i32x4 v4; } ph, pl;
            #pragma unroll
            for (int half = 0; half < 2; half++) {
                const int i = 2 * p + half;
                #pragma unroll
                for (int e = 0; e < 4; e++) {
                    float a = v[i][e];
                    unsigned short hi = f2bf(a);
                    ph.u16[4 * half + e] = hi;
                    pl.u16[4 * half + e] = f2bf(a - bf2f(hi));
                }
            }
            PH[p] = ph.v4; PL[p] = pl.v4;
        }
        // phase-1 writers (cols 0..191) store now
        if (u < 4) {
            #pragma unroll
            for (int p = 0; p < 6; p++) {
                const int sl   = 6 * u + p;                      // local 16B slot 0..23
                const int boff = (sl * 16) ^ ((r & 7) << 4);     // XOR swizzle
                *(i32x4*)(&lds[r * 384 + boff])         = PH[p];
                *(i32x4*)(&lds[12288 + r * 384 + boff]) = PL[p];
            }
        }
        float s = 0.f;
        #pragma unroll
        for (int i = 0; i < 12; i++) {
            #pragma unroll
            for (int e = 0; e < 4; e++) s += v[i][e];
        }
        s += __shfl_xor(s, 1); s += __shfl_xor(s, 2); s += __shfl_xor(s, 4);
        mu = s * (1.f / 384.f);
        float sd = 0.f;
        #pragma unroll
        for (int i = 0; i < 12; i++) {
            #pragma unroll
            for (int e = 0; e < 4; e++) { float d = v[i][e] - mu; sd += d * d; }
        }
        sd += __shfl_xor(sd, 1); sd += __shfl_xor(sd, 2); sd += __shfl_xor(sd, 4);
        rs = rsqrtf(sd * (1.f / 384.f) + LN_EPS);
    }

    // ---------------- MFMA with counted-vmcnt W pipeline across 2 K-phases ----------------
    f32x4 acc[2][3];
    #pragma unroll
    for (int mf = 0; mf < 2; mf++)
        #pragma unroll
        for (int t = 0; t < 3; t++) acc[mf][t] = (f32x4){0.f, 0.f, 0.f, 0.f};

    bf16x8 B0[3], B1[3], B2[3];
    auto issue = [&](int KK, bf16x8* Bb) {
        const bf16x8* bp = (const bf16x8*)wsh + ((KK * 12 + 3 * wv) * 64 + l);
        asm volatile("global_load_dwordx4 %0, %1, off" : "=v"(Bb[0]) : "v"(bp));
        asm volatile("global_load_dwordx4 %0, %1, off" : "=v"(Bb[1]) : "v"(bp + 64));
        asm volatile("global_load_dwordx4 %0, %1, off" : "=v"(Bb[2]) : "v"(bp + 128));
    };
    auto consume = [&](int KK, const bf16x8* Bb) {
        const int kl = KK >= 6 ? KK - 6 : KK;            // local K-step in stage window
        #pragma unroll
        for (int mf = 0; mf < 2; mf++) {
            const int row  = 16 * mf + cl;
            const int boff = (kl * 64 + g * 16) ^ ((row & 7) << 4);
            bf16x8 afh = *(const bf16x8*)(&lds[row * 384 + boff]);
            bf16x8 afl = *(const bf16x8*)(&lds[12288 + row * 384 + boff]);
            #pragma unroll
            for (int t = 0; t < 3; t++) {
                acc[mf][t] = __builtin_amdgcn_mfma_f32_16x16x32_bf16(afh, Bb[t], acc[mf][t], 0, 0, 0);
                acc[mf][t] = __builtin_amdgcn_mfma_f32_16x16x32_bf16(afl, Bb[t], acc[mf][t], 0, 0, 0);
            }
        }
    };

    issue(0, B0); issue(1, B1);          // prologue (drained by first barrier; values land in regs)
    __syncthreads();                     // phase-1 A visible

    #define STEP(KK, BUF, NXTBUF, VM)                                   \
        do {                                                            \
            if ((KK) + 2 < 12) issue((KK) + 2, NXTBUF);                 \
            asm volatile("s_waitcnt vmcnt(" #VM ")" ::: "memory");      \
            __builtin_amdgcn_sched_barrier(0);                          \
            consume((KK), BUF);                                         \
        } while (0)

    STEP(0, B0, B2, 6);
    STEP(1, B1, B0, 6);
    STEP(2, B2, B1, 6);
    STEP(3, B0, B2, 6);
    STEP(4, B1, B0, 6);   // issues kk6 into B0
    STEP(5, B2, B1, 6);   // issues kk7 into B1

    __syncthreads();      // all phase-1 A-reads done (also drains vmcnt: kk6/7 W in regs)
    if (u >= 4) {         // phase-2 writers (cols 192..383)
        #pragma unroll
        for (int p = 0; p < 6; p++) {
            const int sl   = 6 * (u - 4) + p;
            const int boff = (sl * 16) ^ ((r & 7) << 4);
            *(i32x4*)(&lds[r * 384 + boff])         = PH[p];
            *(i32x4*)(&lds[12288 + r * 384 + boff]) = PL[p];
        }
    }
    __syncthreads();      // phase-2 A visible

    STEP(6,  B0, B2, 6);
    STEP(7,  B1, B0, 6);
    STEP(8,  B2, B1, 6);
    STEP(9,  B0, B2, 6);
    STEP(10, B1, B0, 3);
    STEP(11, B2, B1, 0);
    #undef STEP
    __builtin_amdgcn_sched_barrier(0);
    __syncthreads();      // all phase-2 A-reads done; reuse LDS for xs

    // ---------------- xs(raw acc) -> LDS f32 [32][196] ----------------
    {
        float* xsl = (float*)lds;
        #pragma unroll
        for (int mf = 0; mf < 2; mf++)
            #pragma unroll
            for (int t = 0; t < 3; t++) {
                const int col = 48 * wv + 16 * t + cl;   // D: col=lane&15, row=4*(lane>>4)+reg
                #pragma unroll
                for (int rg = 0; rg < 4; rg++) {
                    const int row = 16 * mf + 4 * g + rg;
                    xsl[row * 196 + col] = acc[mf][t][rg];
                }
            }
    }
    __syncthreads();

    // ---------------- epilogue: folded merge-LN affine + 3 chained LNs ----------------
    {
        const float* rowp = (const float*)lds + r * 196 + u * 24;
        float vv[24];
        #pragma unroll
        for (int i = 0; i < 6; i++) {
            f32x4 t4 = *(const f32x4*)(rowp + 4 * i);
            #pragma unroll
            for (int e = 0; e < 4; e++) vv[4 * i + e] = t4[e];
        }
        {
            const f32x4* s2v = (const f32x4*)(s2p + u * 24);
            const f32x4* c0v = (const f32x4*)(c0p + u * 24);
            #pragma unroll
            for (int i = 0; i < 6; i++) {
                f32x4 sv = s2v[i], cv = c0v[i];
                #pragma unroll
                for (int e = 0; e < 4; e++)
                    vv[4 * i + e] = rs * (vv[4 * i + e] - mu * sv[e]) + cv[e];
            }
        }
        float s1 = 0.f;
        #pragma unroll
        for (int i = 0; i < 24; i++) s1 += vv[i];
        s1 += __shfl_xor(s1, 1); s1 += __shfl_xor(s1, 2); s1 += __shfl_xor(s1, 4);
        const float mu1 = s1 * (1.f / 192.f);
        float d1 = 0.f;
        #pragma unroll
        for (int i = 0; i < 24; i++) { float d = vv[i] - mu1; d1 += d * d; }
        d1 += __shfl_xor(d1, 1); d1 += __shfl_xor(d1, 2); d1 += __shfl_xor(d1, 4);
        const float r1 = rsqrtf(d1 * (1.f / 192.f) + LN_EPS);

        const f32x4* vwv = (const f32x4*)(vw + u * 24);
        const f32x4* vbv = (const f32x4*)(vb + u * 24);
        float s2s = 0.f;
        #pragma unroll
        for (int i = 0; i < 6; i++) {
            f32x4 w4 = vwv[i], b4 = vbv[i];
            #pragma unroll
            for (int e = 0; e < 4; e++) {
                float xs0 = vv[4 * i + e];
                float xv0 = xs0 + (xs0 - mu1) * r1 * w4[e] + b4[e];
                vv[4 * i + e] = xv0;
                s2s += xv0;
            }
        }
        s2s += __shfl_xor(s2s, 1); s2s += __shfl_xor(s2s, 2); s2s += __shfl_xor(s2s, 4);
        const float mu2 = s2s * (1.f / 192.f);
        float d2 = 0.f;
        #pragma unroll
        for (int i = 0; i < 24; i++) { float d = vv[i] - mu2; d2 += d * d; }
        d2 += __shfl_xor(d2, 1); d2 += __shfl_xor(d2, 2); d2 += __shfl_xor(d2, 4);
        const float r2 = rsqrtf(d2 * (1.f / 192.f) + LN_EPS);

        const f32x4* awv = (const f32x4*)(aw + u * 24);
        const f32x4* abv = (const f32x4*)(ab + u * 24);
        float s3 = 0.f;
        #pragma unroll
        for (int i = 0; i < 6; i++) {
            f32x4 w4 = awv[i], b4 = abv[i];
            #pragma unroll
            for (int e = 0; e < 4; e++) {
                float xa0 = (vv[4 * i + e] - mu2) * r2 * w4[e] + b4[e];
                vv[4 * i + e] = xa0;
                s3 += xa0;
            }
        }
        s3 += __shfl_xor(s3, 1); s3 += __shfl_xor(s3, 2); s3 += __shfl_xor(s3, 4);
        const float mu3 = s3 * (1.f / 192.f);
        float d3 = 0.f;
        #pragma unroll
        for (int i = 0; i < 24; i++) { float d = vv[i] - mu3; d3 += d * d; }
        d3 += __shfl_xor(d3, 1); d3 += __shfl_xor(d3, 2); d3 += __shfl_xor(d3, 4);
        const float r3 = rsqrtf(d3 * (1.f / 192.f) + LN_EPS);

        const f32x4* fwv = (const f32x4*)(fw + u * 24);
        const f32x4* fbv = (const f32x4*)(fb + u * 24);
        float* op = out + (size_t)(blockIdx.x * 32 + r) * 192 + u * 24;
        #pragma unroll
        for (int i = 0; i < 6; i++) {
            f32x4 w4 = fwv[i], b4 = fbv[i];
            f32x4 o4;
            #pragma unroll
            for (int e = 0; e < 4; e++)
                o4[e] = (vv[4 * i + e] - mu3) * r3 * w4[e] + b4[e];
            *(f32x4*)(op + 4 * i) = o4;
        }
    }
}

// =============== fallback (no workspace): round-8 style fused, inline W cvt ===============
__global__ __launch_bounds__(256, 3)
void fused_fallback(const float* __restrict__ x,
                    const float* __restrict__ Wf,
                    const float* __restrict__ mw, const float* __restrict__ mb,
                    const float* __restrict__ vw, const float* __restrict__ vb,
                    const float* __restrict__ aw, const float* __restrict__ ab,
                    const float* __restrict__ fw, const float* __restrict__ fb,
                    float* __restrict__ out) {
    __shared__ __align__(16) unsigned char lds[49152];
    const int tid = threadIdx.x;
    const int r   = tid >> 3;
    const int u   = tid & 7;
    const int q   = u >> 1;
    const int hh  = u & 1;
    const int wv = tid >> 6;
    const int l  = tid & 63;
    const int g  = l >> 4;
    const int cl = l & 15;

    {
        const int R   = blockIdx.x * 32 + r;
        const int b   = R / 12544;
        const int rem = R - b * 12544;
        const int h2  = rem / 112;
        const int w2  = rem - h2 * 112;
        const int h   = 2 * h2 + (q & 1);
        const int w   = 2 * w2 + (q >> 1);
        const f32x4* src = (const f32x4*)(x + (((size_t)b * 224 + h) * 224 + w) * 96 + hh * 48);
        f32x4 v[12];
        #pragma unroll
        for (int i = 0; i < 12; i++) v[i] = src[i];
        float s = 0.f;
        #pragma unroll
        for (int i = 0; i < 12; i++)
            #pragma unroll
            for (int e = 0; e < 4; e++) s += v[i][e];
        s += __shfl_xor(s, 1); s += __shfl_xor(s, 2); s += __shfl_xor(s, 4);
        const float mu = s * (1.f / 384.f);
        float sd = 0.f;
        #pragma unroll
        for (int i = 0; i < 12; i++)
            #pragma unroll
            for (int e = 0; e < 4; e++) { float d = v[i][e] - mu; sd += d * d; }
        sd += __shfl_xor(sd, 1); sd += __shfl_xor(sd, 2); sd += __shfl_xor(sd, 4);
        const float rs = rsqrtf(sd * (1.f / 384.f) + LN_EPS);
        const f32x4* mwv = (const f32x4*)(mw + q * 96 + hh * 48);
        const f32x4* mbv = (const f32x4*)(mb + q * 96 + hh * 48);
        #pragma unroll
        for (int p = 0; p < 6; p++) {
            union { unsigned short u16[8]; i32x4 v4; } ph, pl;
            #pragma unroll
            for (int half = 0; half < 2; half++) {
                const int i = 2 * p + half;
                f32x4 w4 = mwv[i], b4 = mbv[i];
                #pragma unroll
                for (int e = 0; e < 4; e++) {
                    float a = (v[i][e] - mu) * rs * w4[e] + b4[e];
                    unsigned short hi = f2bf(a);
                    ph.u16[4 * half + e] = hi;
                    pl.u16[4 * half + e] = f2bf(a - bf2f(hi));
                }
            }
            const int slot = 6 * u + p;
            const int boff = (slot * 16) ^ ((r & 7) << 4);
            *(i32x4*)(&lds[r * 768 + boff])         = ph.v4;
            *(i32x4*)(&lds[24576 + r * 768 + boff]) = pl.v4;
        }
    }
    __syncthreads();

    f32x4 acc[2][3];
    #pragma unroll
    for (int mf = 0; mf < 2; mf++)
        #pragma unroll
        for (int t = 0; t < 3; t++) acc[mf][t] = (f32x4){0.f, 0.f, 0.f, 0.f};
    #pragma unroll
    for (int kk = 0; kk < 12; kk++) {
        bf16x8 bh[3];
        #pragma unroll
        for (int t = 0; t < 3; t++) {
            const int n = (3 * wv + t) * 16 + cl;
            const float* wp = Wf + n * 384 + kk * 32 + g * 8;
            f32x4 lo = *(const f32x4*)wp;
            f32x4 hi4 = *(const f32x4*)(wp + 4);
            bf16x8 hbb;
            #pragma unroll
            for (int e = 0; e < 4; e++) { hbb[e] = (short)f2bf(lo[e]); hbb[4 + e] = (short)f2bf(hi4[e]); }
            bh[t] = hbb;
        }
        #pragma unroll
        for (int mf = 0; mf < 2; mf++) {
            const int row  = 16 * mf + cl;
            const int boff = (kk * 64 + g * 16) ^ ((row & 7) << 4);
            bf16x8 afh = *(const bf16x8*)(&lds[row * 768 + boff]);
            bf16x8 afl = *(const bf16x8*)(&lds[24576 + row * 768 + boff]);
            #pragma unroll
            for (int t = 0; t < 3; t++) {
                acc[mf][t] = __builtin_amdgcn_mfma_f32_16x16x32_bf16(afh, bh[t], acc[mf][t], 0, 0, 0);
                acc[mf][t] = __builtin_amdgcn_mfma_f32_16x16x32_bf16(afl, bh[t], acc[mf][t], 0, 0, 0);
            }
        }
    }
    __syncthreads();
    {
        float* xsl = (float*)lds;
        #pragma unroll
        for (int mf = 0; mf < 2; mf++)
            #pragma unroll
            for (int t = 0; t < 3; t++) {
                const int col = 48 * wv + 16 * t + cl;
                #pragma unroll
                for (int rg = 0; rg < 4; rg++) {
                    const int row = 16 * mf + 4 * g + rg;
                    xsl[row * 196 + col] = acc[mf][t][rg];
                }
            }
    }
    __syncthreads();
    {
        const float* rowp = (const float*)lds + r * 196 + u * 24;
        float vv[24];
        #pragma unroll
        for (int i = 0; i < 6; i++) {
            f32x4 t4 = *(const f32x4*)(rowp + 4 * i);
            #pragma unroll
            for (int e = 0; e < 4; e++) vv[4 * i + e] = t4[e];
        }
        float s1 = 0.f;
        #pragma unroll
        for (int i = 0; i < 24; i++) s1 += vv[i];
        s1 += __shfl_xor(s1, 1); s1 += __shfl_xor(s1, 2); s1 += __shfl_xor(s1, 4);
        const float mu1 = s1 * (1.f / 192.f);
        float d1 = 0.f;
        #pragma unroll
        for (int i = 0; i < 24; i++) { float d = vv[i] - mu1; d1 += d * d; }
        d1 += __shfl_xor(d1, 1); d1 += __shfl_xor(d1, 2); d1 += __shfl_xor(d1, 4);
        const float r1 = rsqrtf(d1 * (1.f / 192.f) + LN_EPS);
        const f32x4* vwv = (const f32x4*)(vw + u * 24);
        const f32x4* vbv = (const f32x4*)(vb + u * 24);
        float s2s = 0.f;
        #pragma unroll
        for (int i = 0; i < 6; i++) {
            f32x4 w4 = vwv[i], b4 = vbv[i];
            #pragma unroll
            for (int e = 0; e < 4; e++) {
                float xs0 = vv[4 * i + e];
                float xv0 = xs0 + (xs0 - mu1) * r1 * w4[e] + b4[e];
                vv[4 * i + e] = xv0;
                s2s += xv0;
            }
        }
        s2s += __shfl_xor(s2s, 1); s2s += __shfl_xor(s2s, 2); s2s += __shfl_xor(s2s, 4);
        const float mu2 = s2s * (1.f / 192.f);
        float d2 = 0.f;
        #pragma unroll
        for (int i = 0; i < 24; i++) { float d = vv[i] - mu2; d2 += d * d; }
        d2 += __shfl_xor(d2, 1); d2 += __shfl_xor(d2, 2); d2 += __shfl_xor(d2, 4);
        const float r2 = rsqrtf(d2 * (1.f / 192.f) + LN_EPS);
        const f32x4* awv = (const f32x4*)(aw + u * 24);
        const f32x4* abv = (const f32x4*)(ab + u * 24);
        float s3 = 0.f;
        #pragma unroll
        for (int i = 0; i < 6; i++) {
            f32x4 w4 = awv[i], b4 = abv[i];
            #pragma unroll
            for (int e = 0; e < 4; e++) {
                float xa0 = (vv[4 * i + e] - mu2) * r2 * w4[e] + b4[e];
                vv[4 * i + e] = xa0;
                s3 += xa0;
            }
        }
        s3 += __shfl_xor(s3, 1); s3 += __shfl_xor(s3, 2); s3 += __shfl_xor(s3, 4);
        const float mu3 = s3 * (1.f / 192.f);
        float d3 = 0.f;
        #pragma unroll
        for (int i = 0; i < 24; i++) { float d = vv[i] - mu3; d3 += d * d; }
        d3 += __shfl_xor(d3, 1); d3 += __shfl_xor(d3, 2); d3 += __shfl_xor(d3, 4);
        const float r3 = rsqrtf(d3 * (1.f / 192.f) + LN_EPS);
        const f32x4* fwv = (const f32x4*)(fw + u * 24);
        const f32x4* fbv = (const f32x4*)(fb + u * 24);
        float* op = out + (size_t)(blockIdx.x * 32 + r) * 192 + u * 24;
        #pragma unroll
        for (int i = 0; i < 6; i++) {
            f32x4 w4 = fwv[i], b4 = fbv[i];
            f32x4 o4;
            #pragma unroll
            for (int e = 0; e < 4; e++)
                o4[e] = (vv[4 * i + e] - mu3) * r3 * w4[e] + b4[e];
            *(f32x4*)(op + 4 * i) = o4;
        }
    }
}

extern "C" void kernel_launch(void* const* d_in, const int* in_sizes, int n_in,
                              void* d_out, int out_size, void* d_ws, size_t ws_size,
                              hipStream_t stream) {
    const float* x  = (const float*)d_in[0];
    /* d_in[1] saliency_map: dead code in reference */
    const float* W  = (const float*)d_in[2];
    const float* mw = (const float*)d_in[3];
    const float* mb = (const float*)d_in[4];
    const float* vw = (const float*)d_in[5];
    const float* vb = (const float*)d_in[6];
    const float* aw = (const float*)d_in[7];
    const float* ab = (const float*)d_in[8];
    const float* fw = (const float*)d_in[9];
    const float* fb = (const float*)d_in[10];
    float* out = (float*)d_out;

    const int rows   = 8 * 112 * 112;     // 100352
    const int blocks = rows / 32;         // 3136

    unsigned short* wsh = (unsigned short*)d_ws;
    float* s2 = (float*)((char*)d_ws + 192 * 384 * 2);
    float* c0 = s2 + 192;

    if (ws_size >= (size_t)(192 * 384 * 2 + 2 * 192 * 4)) {
        prep_all_kernel<<<336, 256, 0, stream>>>(W, mw, mb, wsh, s2, c0);
        fused_split<<<blocks, 256, 0, stream>>>(x, wsh, s2, c0,
                                                vw, vb, aw, ab, fw, fb, out);
    } else {
        fused_fallback<<<blocks, 256, 0, stream>>>(x, W, mw, mb, vw, vb,
                                                   aw, ab, fw, fb, out);
    }
}